// Round 1
// baseline (442.810 us; speedup 1.0000x reference)
//
#include <hip/hip_runtime.h>
#include <math.h>

#define BS 64
#define NN 1024
#define T  1200
#define NSEQ (BS * NN)   // 65536

// Per-wave LDS layout: x[0..1199] | A[1200..1799] | B[1800..1999]
// Chain: conv(k2,s2) 1200->600 (A); pool3+relu ->200 (B); conv(k4,s2,p1) ->100 (A);
// pool2+relu ->50 (B); conv(k4,s2,p1) ->25 (A); pool2+relu ->12 (B);
// conv(k4,s2,p1) ->6 (A); pool2+relu ->3 (B); conv(k3,s1) ->1 scalar.

__global__ __launch_bounds__(256) void chain_kernel(
    const float* __restrict__ x,
    const float* __restrict__ c0_w, const float* __restrict__ c0_b,
    const float* __restrict__ c2_w, const float* __restrict__ c2_b,
    const float* __restrict__ c4_w, const float* __restrict__ c4_b,
    const float* __restrict__ c6_w, const float* __restrict__ c6_b,
    const float* __restrict__ c8_w, const float* __restrict__ c8_b,
    float* __restrict__ feat)
{
    __shared__ __align__(16) float smem[4][2000];
    const int wave = threadIdx.x >> 6;
    const int lane = threadIdx.x & 63;
    const int seq  = blockIdx.x * 4 + wave;

    float* sx = smem[wave];
    float* sA = sx + 1200;
    float* sB = sx + 1800;

    // Broadcast weights (uniform scalar loads)
    const float w00 = c0_w[0], w01 = c0_w[1], b0 = c0_b[0];
    const float w20 = c2_w[0], w21 = c2_w[1], w22 = c2_w[2], w23 = c2_w[3], b2 = c2_b[0];
    const float w40 = c4_w[0], w41 = c4_w[1], w42 = c4_w[2], w43 = c4_w[3], b4 = c4_b[0];
    const float w60 = c6_w[0], w61 = c6_w[1], w62 = c6_w[2], w63 = c6_w[3], b6 = c6_b[0];
    const float w80 = c8_w[0], w81 = c8_w[1], w82 = c8_w[2], b8 = c8_b[0];

    // Stage x (1200 floats = 300 float4) coalesced into LDS
    const float4* xg = (const float4*)(x + (size_t)seq * T);
    float4* sx4 = (float4*)sx;
    for (int i = lane; i < 300; i += 64) {
        sx4[i] = xg[i];
    }
    __syncthreads();

    // conv1: k=2, s=2, pad=0 : 1200 -> 600
    for (int j = lane; j < 600; j += 64) {
        sA[j] = w00 * sx[2*j] + w01 * sx[2*j + 1] + b0;
    }
    __syncthreads();

    // maxpool k=3 + relu : 600 -> 200
    for (int p = lane; p < 200; p += 64) {
        float m = fmaxf(sA[3*p], fmaxf(sA[3*p + 1], sA[3*p + 2]));
        sB[p] = fmaxf(m, 0.0f);
    }
    __syncthreads();

    // conv2: k=4, s=2, pad=1 : 200 -> 100
    for (int j = lane; j < 100; j += 64) {
        int base = 2*j - 1;
        float acc = b2;
        float v0 = (base + 0 >= 0   ) ? sB[base + 0] : 0.0f;
        float v3 = (base + 3 <  200 ) ? sB[base + 3] : 0.0f;
        acc += w20 * v0 + w21 * sB[base + 1] + w22 * sB[base + 2] + w23 * v3;
        // note: base+1 in [0,199] and base+2 in [1,200]? j=99: base+2=199 ok; base+1>=0 ok.
        sA[j] = acc;
    }
    __syncthreads();

    // maxpool k=2 + relu : 100 -> 50
    for (int p = lane; p < 50; p += 64) {
        sB[p] = fmaxf(fmaxf(sA[2*p], sA[2*p + 1]), 0.0f);
    }
    __syncthreads();

    // conv3: k=4, s=2, pad=1 : 50 -> 25
    for (int j = lane; j < 25; j += 64) {
        int base = 2*j - 1;
        float acc = b4;
        float v0 = (base + 0 >= 0 ) ? sB[base + 0] : 0.0f;
        float v3 = (base + 3 < 50 ) ? sB[base + 3] : 0.0f;
        acc += w40 * v0 + w41 * sB[base + 1] + w42 * sB[base + 2] + w43 * v3;
        sA[j] = acc;
    }
    __syncthreads();

    // maxpool k=2 + relu : 25 -> 12 (element 24 dropped)
    for (int p = lane; p < 12; p += 64) {
        sB[p] = fmaxf(fmaxf(sA[2*p], sA[2*p + 1]), 0.0f);
    }
    __syncthreads();

    // conv4: k=4, s=2, pad=1 : 12 -> 6
    for (int j = lane; j < 6; j += 64) {
        int base = 2*j - 1;
        float acc = b6;
        float v0 = (base + 0 >= 0 ) ? sB[base + 0] : 0.0f;
        float v3 = (base + 3 < 12 ) ? sB[base + 3] : 0.0f;
        acc += w60 * v0 + w61 * sB[base + 1] + w62 * sB[base + 2] + w63 * v3;
        sA[j] = acc;
    }
    __syncthreads();

    // maxpool k=2 + relu : 6 -> 3
    for (int p = lane; p < 3; p += 64) {
        sB[p] = fmaxf(fmaxf(sA[2*p], sA[2*p + 1]), 0.0f);
    }
    __syncthreads();

    // conv5: k=3, s=1, pad=0 : 3 -> 1  (no relu)
    if (lane == 0) {
        feat[seq] = w80 * sB[0] + w81 * sB[1] + w82 * sB[2] + b8;
    }
}

// Head: logits[b][c] = sum_n feat[b][n] * cls_w[c][n] + cls_b[c]; softmax over c.
__global__ __launch_bounds__(256) void head_kernel(
    const float* __restrict__ feat,
    const float* __restrict__ cls_w,
    const float* __restrict__ cls_b,
    float* __restrict__ out)
{
    const int b = blockIdx.x;
    float a0 = 0.0f, a1 = 0.0f, a2 = 0.0f;
    for (int n = threadIdx.x; n < NN; n += 256) {
        float f = feat[b * NN + n];
        a0 += f * cls_w[0 * NN + n];
        a1 += f * cls_w[1 * NN + n];
        a2 += f * cls_w[2 * NN + n];
    }
    // intra-wave reduction (wave = 64)
    for (int off = 32; off; off >>= 1) {
        a0 += __shfl_down(a0, off);
        a1 += __shfl_down(a1, off);
        a2 += __shfl_down(a2, off);
    }
    __shared__ float red[4][3];
    const int wave = threadIdx.x >> 6;
    const int lane = threadIdx.x & 63;
    if (lane == 0) { red[wave][0] = a0; red[wave][1] = a1; red[wave][2] = a2; }
    __syncthreads();
    if (threadIdx.x == 0) {
        float l0 = red[0][0] + red[1][0] + red[2][0] + red[3][0] + cls_b[0];
        float l1 = red[0][1] + red[1][1] + red[2][1] + red[3][1] + cls_b[1];
        float l2 = red[0][2] + red[1][2] + red[2][2] + red[3][2] + cls_b[2];
        float m  = fmaxf(l0, fmaxf(l1, l2));
        float e0 = expf(l0 - m), e1 = expf(l1 - m), e2 = expf(l2 - m);
        float inv = 1.0f / (e0 + e1 + e2);
        out[b * 3 + 0] = e0 * inv;
        out[b * 3 + 1] = e1 * inv;
        out[b * 3 + 2] = e2 * inv;
    }
}

extern "C" void kernel_launch(void* const* d_in, const int* in_sizes, int n_in,
                              void* d_out, int out_size, void* d_ws, size_t ws_size,
                              hipStream_t stream) {
    const float* x     = (const float*)d_in[0];
    const float* c0_w  = (const float*)d_in[1];
    const float* c0_b  = (const float*)d_in[2];
    const float* c2_w  = (const float*)d_in[3];
    const float* c2_b  = (const float*)d_in[4];
    const float* c4_w  = (const float*)d_in[5];
    const float* c4_b  = (const float*)d_in[6];
    const float* c6_w  = (const float*)d_in[7];
    const float* c6_b  = (const float*)d_in[8];
    const float* c8_w  = (const float*)d_in[9];
    const float* c8_b  = (const float*)d_in[10];
    // d_in[11..14]: gcn weights/biases — dead code in the reference, unused.
    const float* cls_w = (const float*)d_in[15];
    const float* cls_b = (const float*)d_in[16];

    float* feat = (float*)d_ws;   // 65536 floats = 256 KB

    chain_kernel<<<NSEQ / 4, 256, 0, stream>>>(
        x, c0_w, c0_b, c2_w, c2_b, c4_w, c4_b, c6_w, c6_b, c8_w, c8_b, feat);
    head_kernel<<<BS, 256, 0, stream>>>(feat, cls_w, cls_b, (float*)d_out);
}

// Round 2
// 438.149 us; speedup vs baseline: 1.0106x; 1.0106x over previous
//
#include <hip/hip_runtime.h>
#include <math.h>

#define BS 64
#define NN 1024
#define T  1200
#define NSEQ (BS * NN)   // 65536

// Wave-private sync: all data flow is intra-wave (one sequence per wave).
// DS ops from one wave complete in order; this waits for them and stops the
// compiler from caching/reordering LDS accesses across stage boundaries.
#define WAVE_SYNC() asm volatile("s_waitcnt lgkmcnt(0)" ::: "memory")

// Per-wave LDS (1400 floats): x[0..1199] | B[1200..1399]
// After stage1, x region is dead: A2 lives at sx[0..49], A3 at sx[64..75].
// Stages (all fused conv+pool+relu):
//   s1: conv(k2,s2)+pool3+relu  1200 -> 200   (disjoint 6-input groups)
//   s2: conv(k4,s2,p1)+pool2+relu 200 -> 50
//   s3: conv(k4,s2,p1)+pool2+relu  50 -> 12
//   s4: conv(k4,s2,p1)+pool2+relu+conv(k3)  12 -> 1   (lane 0 serial)

__global__ __launch_bounds__(256) void chain_kernel(
    const float* __restrict__ x,
    const float* __restrict__ c0_w, const float* __restrict__ c0_b,
    const float* __restrict__ c2_w, const float* __restrict__ c2_b,
    const float* __restrict__ c4_w, const float* __restrict__ c4_b,
    const float* __restrict__ c6_w, const float* __restrict__ c6_b,
    const float* __restrict__ c8_w, const float* __restrict__ c8_b,
    float* __restrict__ feat)
{
    __shared__ __align__(16) float smem[4][1400];   // 22400 B -> 7 blocks/CU
    const int wave = threadIdx.x >> 6;
    const int lane = threadIdx.x & 63;
    const int seq  = blockIdx.x * 4 + wave;

    float* sx = smem[wave];        // x, later reused for A2/A3
    float* sB = sx + 1200;         // stage1 output (200)

    const float w00 = c0_w[0], w01 = c0_w[1], b0 = c0_b[0];
    const float w20 = c2_w[0], w21 = c2_w[1], w22 = c2_w[2], w23 = c2_w[3], b2 = c2_b[0];
    const float w40 = c4_w[0], w41 = c4_w[1], w42 = c4_w[2], w43 = c4_w[3], b4 = c4_b[0];
    const float w60 = c6_w[0], w61 = c6_w[1], w62 = c6_w[2], w63 = c6_w[3], b6 = c6_b[0];
    const float w80 = c8_w[0], w81 = c8_w[1], w82 = c8_w[2], b8 = c8_b[0];

    // ---- stage0: stage x into LDS, all 5 loads in flight before stores ----
    const float4* xg4 = (const float4*)(x + (size_t)seq * T);   // 300 float4
    float4* sx4 = (float4*)sx;
    float4 r0 = xg4[lane];
    float4 r1 = xg4[lane + 64];
    float4 r2 = xg4[lane + 128];
    float4 r3 = xg4[lane + 192];
    const bool tail = lane < 44;                                // 300 = 4*64 + 44
    float4 r4 = make_float4(0.f, 0.f, 0.f, 0.f);
    if (tail) r4 = xg4[lane + 256];
    sx4[lane]       = r0;
    sx4[lane + 64]  = r1;
    sx4[lane + 128] = r2;
    sx4[lane + 192] = r3;
    if (tail) sx4[lane + 256] = r4;
    WAVE_SYNC();

    // ---- stage1: conv1(k2,s2) + pool3 + relu : 1200 -> 200 ----
    // B[p] = relu(max_{r=0..2} (w00*x[6p+2r] + w01*x[6p+2r+1] + b0))
#pragma unroll
    for (int it = 0; it < 4; ++it) {
        int p = lane + it * 64;
        if (p < 200) {
            const float* xp = sx + 6 * p;
            float x0 = xp[0], x1 = xp[1], x2 = xp[2], x3 = xp[3], x4 = xp[4], x5 = xp[5];
            float c0 = fmaf(w00, x0, fmaf(w01, x1, b0));
            float c1 = fmaf(w00, x2, fmaf(w01, x3, b0));
            float c2 = fmaf(w00, x4, fmaf(w01, x5, b0));
            sB[p] = fmaxf(fmaxf(fmaxf(c0, c1), c2), 0.0f);
        }
    }
    WAVE_SYNC();

    // ---- stage2: conv2(k4,s2,p1) + pool2 + relu : 200 -> 50 (A2 at sx[0..49]) ----
    if (lane < 50) {
        int base = 4 * lane - 1;                       // in [-1, 195]
        float v0 = sB[base < 0 ? 0 : base];
        float v1 = sB[base + 1];
        float v2 = sB[base + 2];
        float v3 = sB[base + 3];
        float v4 = sB[base + 4];
        float v5 = sB[(base + 5) > 199 ? 199 : (base + 5)];
        if (lane == 0)  v0 = 0.0f;                     // left zero-pad
        if (lane == 49) v5 = 0.0f;                     // right zero-pad
        float oa = fmaf(w20, v0, fmaf(w21, v1, fmaf(w22, v2, fmaf(w23, v3, b2))));
        float ob = fmaf(w20, v2, fmaf(w21, v3, fmaf(w22, v4, fmaf(w23, v5, b2))));
        sx[lane] = fmaxf(fmaxf(oa, ob), 0.0f);
    }
    WAVE_SYNC();

    // ---- stage3: conv3(k4,s2,p1) + pool2 + relu : 50 -> 12 (A3 at sx[64..75]) ----
    // pool over out3[2q], out3[2q+1]; out3[24] is dropped (25 -> 12), max read idx = 48.
    if (lane < 12) {
        int base = 4 * lane - 1;                       // in [-1, 43]
        float u0 = sx[base < 0 ? 0 : base];
        float u1 = sx[base + 1];
        float u2 = sx[base + 2];
        float u3 = sx[base + 3];
        float u4 = sx[base + 4];
        float u5 = sx[base + 5];
        if (lane == 0) u0 = 0.0f;
        float oa = fmaf(w40, u0, fmaf(w41, u1, fmaf(w42, u2, fmaf(w43, u3, b4))));
        float ob = fmaf(w40, u2, fmaf(w41, u3, fmaf(w42, u4, fmaf(w43, u5, b4))));
        sx[64 + lane] = fmaxf(fmaxf(oa, ob), 0.0f);
    }
    WAVE_SYNC();

    // ---- stage4: conv4(k4,s2,p1) + pool2 + relu + conv5(k3) : 12 -> 1 (lane 0) ----
    if (lane == 0) {
        float a3[14];                                  // zero-padded A3
        a3[0] = 0.0f; a3[13] = 0.0f;
#pragma unroll
        for (int j = 0; j < 12; ++j) a3[j + 1] = sx[64 + j];
        float o[6];
#pragma unroll
        for (int j = 0; j < 6; ++j) {
            // conv idx 2j-1+t -> shifted a3[2j+t], t=0..3
            o[j] = fmaf(w60, a3[2 * j], fmaf(w61, a3[2 * j + 1],
                   fmaf(w62, a3[2 * j + 2], fmaf(w63, a3[2 * j + 3], b6))));
        }
        float A40 = fmaxf(fmaxf(o[0], o[1]), 0.0f);
        float A41 = fmaxf(fmaxf(o[2], o[3]), 0.0f);
        float A42 = fmaxf(fmaxf(o[4], o[5]), 0.0f);
        feat[seq] = fmaf(w80, A40, fmaf(w81, A41, fmaf(w82, A42, b8)));
    }
}

// Head: logits[b][c] = sum_n feat[b][n] * cls_w[c][n] + cls_b[c]; softmax over c.
__global__ __launch_bounds__(256) void head_kernel(
    const float* __restrict__ feat,
    const float* __restrict__ cls_w,
    const float* __restrict__ cls_b,
    float* __restrict__ out)
{
    const int b = blockIdx.x;
    float a0 = 0.0f, a1 = 0.0f, a2 = 0.0f;
    for (int n = threadIdx.x; n < NN; n += 256) {
        float f = feat[b * NN + n];
        a0 += f * cls_w[0 * NN + n];
        a1 += f * cls_w[1 * NN + n];
        a2 += f * cls_w[2 * NN + n];
    }
    for (int off = 32; off; off >>= 1) {
        a0 += __shfl_down(a0, off);
        a1 += __shfl_down(a1, off);
        a2 += __shfl_down(a2, off);
    }
    __shared__ float red[4][3];
    const int wave = threadIdx.x >> 6;
    const int lane = threadIdx.x & 63;
    if (lane == 0) { red[wave][0] = a0; red[wave][1] = a1; red[wave][2] = a2; }
    __syncthreads();
    if (threadIdx.x == 0) {
        float l0 = red[0][0] + red[1][0] + red[2][0] + red[3][0] + cls_b[0];
        float l1 = red[0][1] + red[1][1] + red[2][1] + red[3][1] + cls_b[1];
        float l2 = red[0][2] + red[1][2] + red[2][2] + red[3][2] + cls_b[2];
        float m  = fmaxf(l0, fmaxf(l1, l2));
        float e0 = expf(l0 - m), e1 = expf(l1 - m), e2 = expf(l2 - m);
        float inv = 1.0f / (e0 + e1 + e2);
        out[b * 3 + 0] = e0 * inv;
        out[b * 3 + 1] = e1 * inv;
        out[b * 3 + 2] = e2 * inv;
    }
}

extern "C" void kernel_launch(void* const* d_in, const int* in_sizes, int n_in,
                              void* d_out, int out_size, void* d_ws, size_t ws_size,
                              hipStream_t stream) {
    const float* x     = (const float*)d_in[0];
    const float* c0_w  = (const float*)d_in[1];
    const float* c0_b  = (const float*)d_in[2];
    const float* c2_w  = (const float*)d_in[3];
    const float* c2_b  = (const float*)d_in[4];
    const float* c4_w  = (const float*)d_in[5];
    const float* c4_b  = (const float*)d_in[6];
    const float* c6_w  = (const float*)d_in[7];
    const float* c6_b  = (const float*)d_in[8];
    const float* c8_w  = (const float*)d_in[9];
    const float* c8_b  = (const float*)d_in[10];
    // d_in[11..14]: gcn weights/biases — dead code in the reference, unused.
    const float* cls_w = (const float*)d_in[15];
    const float* cls_b = (const float*)d_in[16];

    float* feat = (float*)d_ws;   // 65536 floats = 256 KB

    chain_kernel<<<NSEQ / 4, 256, 0, stream>>>(
        x, c0_w, c0_b, c2_w, c2_b, c4_w, c4_b, c6_w, c6_b, c8_w, c8_b, feat);
    head_kernel<<<BS, 256, 0, stream>>>(feat, cls_w, cls_b, (float*)d_out);
}